// Round 6
// baseline (1385.733 us; speedup 1.0000x reference)
//
#include <hip/hip_runtime.h>
#include <math.h>

#define B_   16
#define N_   2048
#define K_   20
#define C_   64
#define OUT_ 64
#define NEG_SLOPE 0.2f

// ---------------------------------------------------------------------------
// Kernel 1: KNN — one wave per point (bit-identical math to R4/R5).
// ---------------------------------------------------------------------------
__global__ __launch_bounds__(256, 2)
void knn_kernel(const float* __restrict__ pos, int* __restrict__ idx_out) {
    const int t = threadIdx.x;
    const int wv = t >> 6, l = t & 63;
    const int gid = blockIdx.x * 4 + wv;
    const int b = gid / N_, n = gid % N_;
    const float* pb = pos + (size_t)b * 3 * N_;

    const double qx = (double)pb[n];
    const double qy = (double)pb[N_ + n];
    const double qz = (double)pb[2 * N_ + n];
    const double xxn = qx * qx + qy * qy + qz * qz;

    double d[32];
    const int m0 = l * 32;
#pragma unroll
    for (int j4 = 0; j4 < 8; ++j4) {
        float4 px = *(const float4*)(pb + m0 + 4 * j4);
        float4 py = *(const float4*)(pb + N_ + m0 + 4 * j4);
        float4 pz = *(const float4*)(pb + 2 * N_ + m0 + 4 * j4);
#define DCOMP(JJ, PX, PY, PZ)                                            \
        {   double ddx = (double)(PX), ddy = (double)(PY), ddz = (double)(PZ); \
            double inner = qx * ddx + qy * ddy + qz * ddz;               \
            double xxm   = ddx * ddx + ddy * ddy + ddz * ddz;            \
            d[4 * j4 + JJ] = 2.0 * inner - xxn - xxm; }
        DCOMP(0, px.x, py.x, pz.x)
        DCOMP(1, px.y, py.y, pz.y)
        DCOMP(2, px.z, py.z, pz.z)
        DCOMP(3, px.w, py.w, pz.w)
#undef DCOMP
    }

    unsigned sel = 0u;
    for (int r = 0; r < K_ + 1; ++r) {
        double bk = -INFINITY;
        int bi = 0x7FFFFFFF;
#pragma unroll
        for (int j = 0; j < 32; ++j) {
            bool live = ((sel >> j) & 1u) == 0u;
            if (live && d[j] > bk) { bk = d[j]; bi = m0 + j; }
        }
#pragma unroll
        for (int off = 1; off < 64; off <<= 1) {
            double ok = __shfl_xor(bk, off, 64);
            int    oi = __shfl_xor(bi, off, 64);
            if (ok > bk || (ok == bk && oi < bi)) { bk = ok; bi = oi; }
        }
        if ((bi >> 5) == l) sel |= 1u << (bi & 31);
        if (l == 0 && r > 0) idx_out[(size_t)gid * K_ + (r - 1)] = bi;
    }
}

// ---------------------------------------------------------------------------
// Kernel 2: bxT[b][n][o] = sum_c basis_W[o,c] * x[b,c,n]   (transposed out)
// ---------------------------------------------------------------------------
__global__ __launch_bounds__(256)
void bx_kernel_t(const float* __restrict__ x, const float* __restrict__ W,
                 float* __restrict__ bxT) {
    __shared__ float wS[64 * 65];
    __shared__ float xS[64 * 33];
    const int t = threadIdx.x;
    const int b = blockIdx.y;
    const int n0 = blockIdx.x * 32;

    for (int i = t; i < 64 * 64; i += 256) {
        int r = i >> 6, c = i & 63;
        wS[r * 65 + c] = W[i];
    }
    for (int i = t; i < 64 * 32; i += 256) {
        int c = i >> 5, j = i & 31;
        xS[c * 33 + j] = x[((size_t)b * C_ + c) * N_ + n0 + j];
    }
    __syncthreads();

    const int o = t & 63, j0 = t >> 6;
#pragma unroll 1
    for (int j = j0; j < 32; j += 4) {
        float acc = 0.f;
#pragma unroll
        for (int c = 0; c < 64; ++c)
            acc = fmaf(wS[o * 65 + c], xS[c * 33 + j], acc);
        bxT[((size_t)b * N_ + n0 + j) * 64 + o] = acc;
    }
}

// ---------------------------------------------------------------------------
// Kernel 3: fused pipeline — one wave per point.
// R7: weights staged in LDS transposed (removed the per-n L1-miss storms).
// R8: register prefetch (regressed: spilled at the 128-reg cap).
// R9: lb(256,1): no spill (VGPR 180) but occupancy pinned to 1 block/CU.
// R10: amdgpu_waves_per_eu(2,2) ignored — identical codegen to R8.
// R11: fit the kernel UNDER the 128-reg cap instead of fighting it:
//   - prefetch dropped (back to R7 direct per-n loads)
//   - dk_W1/dk_W2 weight loads demoted into their phases (tables are
//     256 B / 2 KB -> permanently L1-resident; frees 24 persistent VGPRs)
//   - att & edge k-loops split into 2 halves of 10 (acc2[10] not [20],
//     halves peak live accumulators; per-k math order identical, max is
//     order-insensitive -> bit-identical output). wEdT/wF2T rows are read
//     twice (conflict-free LDS, cheap).
//   - launch_bounds(256,2): the known 2-blocks/CU config.
// ---------------------------------------------------------------------------
#define WPB 4
#define NPW 4
#define NBLK (WPB * NPW)   // 16 n per block
#define SLICE 2048         // floats per wave slice (8 KB)

__global__ __launch_bounds__(256, 2)
void fused_kernel(const float* __restrict__ x, const float* __restrict__ glf,
                  const float* __restrict__ appf,
                  const float* __restrict__ dk_W1, const float* __restrict__ dk_b1,
                  const float* __restrict__ dk_g1, const float* __restrict__ dk_be1,
                  const float* __restrict__ dk_W2, const float* __restrict__ dk_b2,
                  const float* __restrict__ act_g, const float* __restrict__ act_b,
                  const float* __restrict__ ff_W1, const float* __restrict__ ff_g1,
                  const float* __restrict__ ff_be1, const float* __restrict__ ff_W2,
                  const float* __restrict__ edge_W, const float* __restrict__ edge_g,
                  const float* __restrict__ edge_be,
                  const float* __restrict__ bxT, const int* __restrict__ idx_ws,
                  float* __restrict__ out) {
    __shared__ float wEdT[128 * 64];   // wEdT[c][o] = edge_W[o][c]   (32 KB)
    __shared__ float wF1T[64 * 32];    // wF1T[c][o] = ff_W1[o][c]    (8 KB)
    __shared__ float wF2T[32 * 64];    // wF2T[c][o] = ff_W2[o][c]    (8 KB)
    __shared__ float lds[WPB * SLICE]; // per-wave slices             (32 KB)

    const int t = threadIdx.x, wv = t >> 6, l = t & 63;
    float* Wb   = lds + wv * SLICE;
    float* RIF  = Wb;            // [20][64]
    float* SCR  = Wb + 1280;     // appf [20][8] @0 ; h [20][16] @160 ; t [20][32] @0
    float* XCOL = Wb + 1920;     // 64
    int*   IDX  = (int*)(Wb + 1984); // 20

    // ---- one-time weight staging (coalesced global float4 reads) ----
    for (int i = t; i < 64 * 32; i += 256) {          // edge_W: 64x128
        int o = i >> 5, c4 = i & 31;
        float4 v = ((const float4*)edge_W)[i];
        wEdT[(4 * c4 + 0) * 64 + o] = v.x;
        wEdT[(4 * c4 + 1) * 64 + o] = v.y;
        wEdT[(4 * c4 + 2) * 64 + o] = v.z;
        wEdT[(4 * c4 + 3) * 64 + o] = v.w;
    }
    for (int i = t; i < 32 * 16; i += 256) {          // ff_W1: 32x64
        int o = i >> 4, c4 = i & 15;
        float4 v = ((const float4*)ff_W1)[i];
        wF1T[(4 * c4 + 0) * 32 + o] = v.x;
        wF1T[(4 * c4 + 1) * 32 + o] = v.y;
        wF1T[(4 * c4 + 2) * 32 + o] = v.z;
        wF1T[(4 * c4 + 3) * 32 + o] = v.w;
    }
    for (int i = t; i < 64 * 8; i += 256) {           // ff_W2: 64x32
        int o = i >> 3, c4 = i & 7;
        float4 v = ((const float4*)ff_W2)[i];
        wF2T[(4 * c4 + 0) * 64 + o] = v.x;
        wF2T[(4 * c4 + 1) * 64 + o] = v.y;
        wF2T[(4 * c4 + 2) * 64 + o] = v.z;
        wF2T[(4 * c4 + 3) * 64 + o] = v.w;
    }
    __syncthreads();

    // XCD-aware swizzle: 2048 blocks = 8 XCD x 256; 2 b per XCD, 128 blocks/b.
    const int raw  = blockIdx.x;
    const int xcd  = raw & 7;
    const int slot = raw >> 3;                 // 0..255
    const int b    = xcd * 2 + (slot >> 7);    // 2 b per xcd
    const int nblk = (slot & 127) * NBLK;
    const int nw0  = nblk + wv * NPW;

    // ---- hoisted per-lane constants (n-invariant, scalars only) ----
    const int o16 = l >> 2, o32 = l >> 1;
    const int kq5 = (l & 3) * 5, kh10 = (l & 1) * 10;
    const int l2 = l & 31;
    const float bdk1h = dk_b1[o16], gdk1h = dk_g1[o16], bedk1h = dk_be1[o16];
    const float bdk2h = dk_b2[o32];
    const float gff1h = ff_g1[o32], beff1h = ff_be1[o32];
    const float gacth = act_g[l],  bacth = act_b[l];
    const float gedgh = edge_g[l], beedgh = edge_be[l];
    const float* xrow  = x + ((size_t)b * C_ + l) * N_;
    const float* bxb   = bxT + (size_t)b * N_ * 64;

#pragma unroll 1
    for (int i = 0; i < NPW; ++i) {
        const int n = nw0 + i;

        // ---- per-n loads (direct; no prefetch state) ----
        const float xc = xrow[n];
        XCOL[l] = xc;
        if (l < K_) IDX[l] = idx_ws[((size_t)b * N_ + n) * K_ + l];
        if (l >= 32) {                 // appf: 160 contiguous floats
            const float4* src = (const float4*)(appf + ((size_t)b * N_ + n) * (K_ * 8));
            *(float4*)(SCR + 4 * l2) = src[l2];
            if (l2 < 8) *(float4*)(SCR + 128 + 4 * l2) = src[32 + l2];
        } else {                       // glf row c2=l -> RIF[k][32+l]
            const float* g = glf + (((size_t)b * 32 + l) * N_ + n) * K_;
#pragma unroll
            for (int kc = 0; kc < 5; ++kc) {
                float4 v = *(const float4*)(g + 4 * kc);
                RIF[(4 * kc + 0) * 64 + 32 + l] = v.x;
                RIF[(4 * kc + 1) * 64 + 32 + l] = v.y;
                RIF[(4 * kc + 2) * 64 + 32 + l] = v.z;
                RIF[(4 * kc + 3) * 64 + 32 + l] = v.w;
            }
        }

        // ---- base_l = edge_W[l, 64:128] . x  (weights from LDS) ----
        float base = 0.f;
#pragma unroll
        for (int c = 0; c < 16; ++c) {
            const float w0 = wEdT[(64 + 4 * c + 0) * 64 + l];
            const float w1 = wEdT[(64 + 4 * c + 1) * 64 + l];
            const float w2 = wEdT[(64 + 4 * c + 2) * 64 + l];
            const float w3 = wEdT[(64 + 4 * c + 3) * 64 + l];
            float4 x4 = *(const float4*)(XCOL + 4 * c);
            base = fmaf(w0, x4.x, base); base = fmaf(w1, x4.y, base);
            base = fmaf(w2, x4.z, base); base = fmaf(w3, x4.w, base);
        }

        // ---- h = relu(bn(dk_W1 @ appf + b1)) : lane -> o=l>>2, k=kq5+q ----
        {
            const float4 wd1a = *(const float4*)(dk_W1 + o16 * 8);      // L1-hit
            const float4 wd1b = *(const float4*)(dk_W1 + o16 * 8 + 4);
#pragma unroll
            for (int q = 0; q < 5; ++q) {
                const int k = kq5 + q;
                float4 a0 = *(const float4*)(SCR + k * 8);
                float4 a1 = *(const float4*)(SCR + k * 8 + 4);
                float acc = bdk1h;
                acc = fmaf(wd1a.x, a0.x, acc); acc = fmaf(wd1a.y, a0.y, acc);
                acc = fmaf(wd1a.z, a0.z, acc); acc = fmaf(wd1a.w, a0.w, acc);
                acc = fmaf(wd1b.x, a1.x, acc); acc = fmaf(wd1b.y, a1.y, acc);
                acc = fmaf(wd1b.z, a1.z, acc); acc = fmaf(wd1b.w, a1.w, acc);
                float v = acc * gdk1h + bedk1h;
                SCR[160 + k * 16 + o16] = fmaxf(v, 0.f);
            }
        }

        // ---- rif[0:32] = dk_W2 @ h + b2 : lane -> o=l>>1, k=kh10+q ----
        {
            const float4 wd20 = *(const float4*)(dk_W2 + o32 * 16);     // L1-hit
            const float4 wd21 = *(const float4*)(dk_W2 + o32 * 16 + 4);
            const float4 wd22 = *(const float4*)(dk_W2 + o32 * 16 + 8);
            const float4 wd23 = *(const float4*)(dk_W2 + o32 * 16 + 12);
#pragma unroll
            for (int q = 0; q < 10; ++q) {
                const int k = kh10 + q;
                const float* hr = SCR + 160 + k * 16;
                float4 h0 = *(const float4*)(hr);
                float4 h1 = *(const float4*)(hr + 4);
                float4 h2 = *(const float4*)(hr + 8);
                float4 h3 = *(const float4*)(hr + 12);
                float acc = bdk2h;
                acc = fmaf(wd20.x, h0.x, acc); acc = fmaf(wd20.y, h0.y, acc);
                acc = fmaf(wd20.z, h0.z, acc); acc = fmaf(wd20.w, h0.w, acc);
                acc = fmaf(wd21.x, h1.x, acc); acc = fmaf(wd21.y, h1.y, acc);
                acc = fmaf(wd21.z, h1.z, acc); acc = fmaf(wd21.w, h1.w, acc);
                acc = fmaf(wd22.x, h2.x, acc); acc = fmaf(wd22.y, h2.y, acc);
                acc = fmaf(wd22.z, h2.z, acc); acc = fmaf(wd22.w, h2.w, acc);
                acc = fmaf(wd23.x, h3.x, acc); acc = fmaf(wd23.y, h3.y, acc);
                acc = fmaf(wd23.z, h3.z, acc); acc = fmaf(wd23.w, h3.w, acc);
                RIF[k * 64 + o32] = acc;
            }
        }

        // ---- t = leaky(bn(ff_W1 @ rif)) : lane -> o=l>>1, k=kh10+q ----
        {
            float acc[10];
#pragma unroll
            for (int q = 0; q < 10; ++q) acc[q] = 0.f;
#pragma unroll
            for (int c = 0; c < 16; ++c) {
                const float w0 = wF1T[(4 * c + 0) * 32 + o32];
                const float w1 = wF1T[(4 * c + 1) * 32 + o32];
                const float w2 = wF1T[(4 * c + 2) * 32 + o32];
                const float w3 = wF1T[(4 * c + 3) * 32 + o32];
#pragma unroll
                for (int q = 0; q < 10; ++q) {
                    float4 r4 = *(const float4*)(RIF + (kh10 + q) * 64 + 4 * c);
                    acc[q] = fmaf(w0, r4.x, acc[q]);
                    acc[q] = fmaf(w1, r4.y, acc[q]);
                    acc[q] = fmaf(w2, r4.z, acc[q]);
                    acc[q] = fmaf(w3, r4.w, acc[q]);
                }
            }
#pragma unroll
            for (int q = 0; q < 10; ++q) {
                float v = acc[q] * gff1h + beff1h;
                v = (v >= 0.f) ? v : NEG_SLOPE * v;
                SCR[(kh10 + q) * 32 + o32] = v;   // t overwrites appf/h (dead)
            }
        }

        // ---- att = sigmoid(ff_W2 @ t); feat = relu(bn(rif*att*gather)) - x
        //      split in 2 halves of 10 k to halve live accumulators ----
#pragma unroll 1
        for (int half = 0; half < 2; ++half) {
            const int k0 = half * 10;
            float acc2[10];
#pragma unroll
            for (int k = 0; k < 10; ++k) acc2[k] = 0.f;
#pragma unroll
            for (int c = 0; c < 8; ++c) {
                const float w0 = wF2T[(4 * c + 0) * 64 + l];
                const float w1 = wF2T[(4 * c + 1) * 64 + l];
                const float w2 = wF2T[(4 * c + 2) * 64 + l];
                const float w3 = wF2T[(4 * c + 3) * 64 + l];
#pragma unroll
                for (int k = 0; k < 10; ++k) {
                    float4 t4 = *(const float4*)(SCR + (k0 + k) * 32 + 4 * c);
                    acc2[k] = fmaf(w0, t4.x, acc2[k]);
                    acc2[k] = fmaf(w1, t4.y, acc2[k]);
                    acc2[k] = fmaf(w2, t4.z, acc2[k]);
                    acc2[k] = fmaf(w3, t4.w, acc2[k]);
                }
            }
#pragma unroll
            for (int k = 0; k < 10; ++k) {
                float a = 1.f / (1.f + expf(-acc2[k]));
                int kidx = IDX[k0 + k];
                float gth = bxb[(size_t)kidx * 64 + l];   // L2-hit 256 B row
                float v = RIF[(k0 + k) * 64 + l] * a * gth;
                v = v * gacth + bacth;
                v = fmaxf(v, 0.f) - xc;
                RIF[(k0 + k) * 64 + l] = v;
            }
        }

        // ---- edge conv + bn + leaky + max over k — 2 halves of 10 ----
        float mx = -INFINITY;
#pragma unroll 1
        for (int half = 0; half < 2; ++half) {
            const int k0 = half * 10;
            float acc2[10];
#pragma unroll
            for (int k = 0; k < 10; ++k) acc2[k] = base;
#pragma unroll
            for (int c = 0; c < 16; ++c) {
                const float w0 = wEdT[(4 * c + 0) * 64 + l];
                const float w1 = wEdT[(4 * c + 1) * 64 + l];
                const float w2 = wEdT[(4 * c + 2) * 64 + l];
                const float w3 = wEdT[(4 * c + 3) * 64 + l];
#pragma unroll
                for (int k = 0; k < 10; ++k) {
                    float4 r4 = *(const float4*)(RIF + (k0 + k) * 64 + 4 * c);
                    acc2[k] = fmaf(w0, r4.x, acc2[k]);
                    acc2[k] = fmaf(w1, r4.y, acc2[k]);
                    acc2[k] = fmaf(w2, r4.z, acc2[k]);
                    acc2[k] = fmaf(w3, r4.w, acc2[k]);
                }
            }
#pragma unroll
            for (int k = 0; k < 10; ++k) {
                float v = acc2[k] * gedgh + beedgh;
                v = (v >= 0.f) ? v : NEG_SLOPE * v;
                mx = fmaxf(mx, v);
            }
        }
        out[((size_t)b * OUT_ + l) * N_ + n] = mx;
    }
}

// ---------------------------------------------------------------------------
extern "C" void kernel_launch(void* const* d_in, const int* in_sizes, int n_in,
                              void* d_out, int out_size, void* d_ws, size_t ws_size,
                              hipStream_t stream) {
    (void)in_sizes; (void)n_in; (void)out_size; (void)ws_size;
    const float* pos     = (const float*)d_in[0];
    const float* x       = (const float*)d_in[1];
    const float* glf     = (const float*)d_in[2];
    const float* appf    = (const float*)d_in[3];
    const float* basis_W = (const float*)d_in[4];
    const float* dk_W1   = (const float*)d_in[5];
    const float* dk_b1   = (const float*)d_in[6];
    const float* dk_g1   = (const float*)d_in[7];
    const float* dk_be1  = (const float*)d_in[8];
    const float* dk_W2   = (const float*)d_in[9];
    const float* dk_b2   = (const float*)d_in[10];
    const float* act_g   = (const float*)d_in[11];
    const float* act_b   = (const float*)d_in[12];
    const float* ff_W1   = (const float*)d_in[13];
    const float* ff_g1   = (const float*)d_in[14];
    const float* ff_be1  = (const float*)d_in[15];
    const float* ff_W2   = (const float*)d_in[16];
    const float* edge_W  = (const float*)d_in[17];
    const float* edge_g  = (const float*)d_in[18];
    const float* edge_be = (const float*)d_in[19];
    float* out = (float*)d_out;

    int*   idx_ws = (int*)d_ws;
    float* bxT    = (float*)((char*)d_ws + (size_t)B_ * N_ * K_ * sizeof(int));

    hipLaunchKernelGGL(knn_kernel, dim3(B_ * N_ / 4), dim3(256), 0, stream,
                       pos, idx_ws);
    hipLaunchKernelGGL(bx_kernel_t, dim3(N_ / 32, B_), dim3(256), 0, stream,
                       x, basis_W, bxT);
    hipLaunchKernelGGL(fused_kernel, dim3(B_ * (N_ / NBLK)), dim3(256), 0, stream,
                       x, glf, appf, dk_W1, dk_b1, dk_g1, dk_be1, dk_W2, dk_b2,
                       act_g, act_b, ff_W1, ff_g1, ff_be1, ff_W2,
                       edge_W, edge_g, edge_be, bxT, idx_ws, out);
}

// Round 7
// 1127.118 us; speedup vs baseline: 1.2294x; 1.2294x over previous
//
#include <hip/hip_runtime.h>
#include <math.h>

#define B_   16
#define N_   2048
#define K_   20
#define C_   64
#define OUT_ 64
#define NEG_SLOPE 0.2f

// ---------------------------------------------------------------------------
// Kernel 1: KNN — one wave per point (bit-identical math to R4/R5).
// ---------------------------------------------------------------------------
__global__ __launch_bounds__(256, 2)
void knn_kernel(const float* __restrict__ pos, int* __restrict__ idx_out) {
    const int t = threadIdx.x;
    const int wv = t >> 6, l = t & 63;
    const int gid = blockIdx.x * 4 + wv;
    const int b = gid / N_, n = gid % N_;
    const float* pb = pos + (size_t)b * 3 * N_;

    const double qx = (double)pb[n];
    const double qy = (double)pb[N_ + n];
    const double qz = (double)pb[2 * N_ + n];
    const double xxn = qx * qx + qy * qy + qz * qz;

    double d[32];
    const int m0 = l * 32;
#pragma unroll
    for (int j4 = 0; j4 < 8; ++j4) {
        float4 px = *(const float4*)(pb + m0 + 4 * j4);
        float4 py = *(const float4*)(pb + N_ + m0 + 4 * j4);
        float4 pz = *(const float4*)(pb + 2 * N_ + m0 + 4 * j4);
#define DCOMP(JJ, PX, PY, PZ)                                            \
        {   double ddx = (double)(PX), ddy = (double)(PY), ddz = (double)(PZ); \
            double inner = qx * ddx + qy * ddy + qz * ddz;               \
            double xxm   = ddx * ddx + ddy * ddy + ddz * ddz;            \
            d[4 * j4 + JJ] = 2.0 * inner - xxn - xxm; }
        DCOMP(0, px.x, py.x, pz.x)
        DCOMP(1, px.y, py.y, pz.y)
        DCOMP(2, px.z, py.z, pz.z)
        DCOMP(3, px.w, py.w, pz.w)
#undef DCOMP
    }

    unsigned sel = 0u;
    for (int r = 0; r < K_ + 1; ++r) {
        double bk = -INFINITY;
        int bi = 0x7FFFFFFF;
#pragma unroll
        for (int j = 0; j < 32; ++j) {
            bool live = ((sel >> j) & 1u) == 0u;
            if (live && d[j] > bk) { bk = d[j]; bi = m0 + j; }
        }
#pragma unroll
        for (int off = 1; off < 64; off <<= 1) {
            double ok = __shfl_xor(bk, off, 64);
            int    oi = __shfl_xor(bi, off, 64);
            if (ok > bk || (ok == bk && oi < bi)) { bk = ok; bi = oi; }
        }
        if ((bi >> 5) == l) sel |= 1u << (bi & 31);
        if (l == 0 && r > 0) idx_out[(size_t)gid * K_ + (r - 1)] = bi;
    }
}

// ---------------------------------------------------------------------------
// Kernel 2: bxT[b][n][o] = sum_c basis_W[o,c] * x[b,c,n]   (transposed out)
// ---------------------------------------------------------------------------
__global__ __launch_bounds__(256)
void bx_kernel_t(const float* __restrict__ x, const float* __restrict__ W,
                 float* __restrict__ bxT) {
    __shared__ float wS[64 * 65];
    __shared__ float xS[64 * 33];
    const int t = threadIdx.x;
    const int b = blockIdx.y;
    const int n0 = blockIdx.x * 32;

    for (int i = t; i < 64 * 64; i += 256) {
        int r = i >> 6, c = i & 63;
        wS[r * 65 + c] = W[i];
    }
    for (int i = t; i < 64 * 32; i += 256) {
        int c = i >> 5, j = i & 31;
        xS[c * 33 + j] = x[((size_t)b * C_ + c) * N_ + n0 + j];
    }
    __syncthreads();

    const int o = t & 63, j0 = t >> 6;
#pragma unroll 1
    for (int j = j0; j < 32; j += 4) {
        float acc = 0.f;
#pragma unroll
        for (int c = 0; c < 64; ++c)
            acc = fmaf(wS[o * 65 + c], xS[c * 33 + j], acc);
        bxT[((size_t)b * N_ + n0 + j) * 64 + o] = acc;
    }
}

// ---------------------------------------------------------------------------
// Kernel 3: fused pipeline — one wave per point.
// R7:  weights in LDS transposed. R8: reg prefetch (spilled @128 cap).
// R9:  lb(256,1): NO SPILL (VGPR 180, FETCH 61 MB) but 1 wave/SIMD (967us).
// R10: waves_per_eu attr ignored. R11: source-level pressure cut backfired
//      (compiler re-hoists loop-invariant loads; spill tripled).
// R12: 512-THREAD BLOCK + lb(512,1) — the structural fix. 8 waves/block
//      MUST co-reside at 2 waves/SIMD, so the allocator cap is pool/2 =
//      256 VGPRs (fits the ~180 demand, no spill) AND the block shape
//      forces 2 waves/SIMD occupancy; the toolchain cannot pin us to 1.
//      LDS 48 KB weights + 8x8 KB slices = 112 KB -> 1 block/CU.
//      Body = R9's no-spill code; only geometry/staging/swizzle changed.
// ---------------------------------------------------------------------------
#define WPB 8
#define NPW 4
#define NBLK (WPB * NPW)   // 32 n per block
#define SLICE 2048         // floats per wave slice (8 KB)

__global__ __launch_bounds__(512, 1)
void fused_kernel(const float* __restrict__ x, const float* __restrict__ glf,
                  const float* __restrict__ appf,
                  const float* __restrict__ dk_W1, const float* __restrict__ dk_b1,
                  const float* __restrict__ dk_g1, const float* __restrict__ dk_be1,
                  const float* __restrict__ dk_W2, const float* __restrict__ dk_b2,
                  const float* __restrict__ act_g, const float* __restrict__ act_b,
                  const float* __restrict__ ff_W1, const float* __restrict__ ff_g1,
                  const float* __restrict__ ff_be1, const float* __restrict__ ff_W2,
                  const float* __restrict__ edge_W, const float* __restrict__ edge_g,
                  const float* __restrict__ edge_be,
                  const float* __restrict__ bxT, const int* __restrict__ idx_ws,
                  float* __restrict__ out) {
    __shared__ float wEdT[128 * 64];   // wEdT[c][o] = edge_W[o][c]   (32 KB)
    __shared__ float wF1T[64 * 32];    // wF1T[c][o] = ff_W1[o][c]    (8 KB)
    __shared__ float wF2T[32 * 64];    // wF2T[c][o] = ff_W2[o][c]    (8 KB)
    __shared__ float lds[WPB * SLICE]; // per-wave slices             (64 KB)

    const int t = threadIdx.x, wv = t >> 6, l = t & 63;
    float* Wb   = lds + wv * SLICE;
    float* RIF  = Wb;            // [20][64]
    float* SCR  = Wb + 1280;     // appf [20][8] @0 ; h [20][16] @160 ; t [20][32] @0
    float* XCOL = Wb + 1920;     // 64
    int*   IDX  = (int*)(Wb + 1984); // 20

    // XCD-aware swizzle: 1024 blocks = 8 XCD x 128; 2 b per XCD, 64 blocks/b.
    const int raw  = blockIdx.x;
    const int xcd  = raw & 7;
    const int slot = raw >> 3;                 // 0..127
    const int b    = xcd * 2 + (slot >> 6);    // 2 b per xcd
    const int nblk = (slot & 63) * NBLK;
    const int nw0  = nblk + wv * NPW;

    const int l2 = l & 31;
    const float* xrow  = x + ((size_t)b * C_ + l) * N_;
    const float* bxb   = bxT + (size_t)b * N_ * 64;

    // ---- prefetch registers (n-ahead global data) ----
    float  xcP = 0.f;
    int    idxP = 0;
    float4 p0, p1, p2, p3, p4;
    p0 = p1 = p2 = p3 = p4 = make_float4(0.f, 0.f, 0.f, 0.f);

#define ISSUE(NN) do {                                                        \
        xcP = xrow[(NN)];                                                     \
        if (l < K_) idxP = idx_ws[((size_t)b * N_ + (NN)) * K_ + l];          \
        if (l >= 32) {                                                        \
            const float4* src =                                               \
                (const float4*)(appf + ((size_t)b * N_ + (NN)) * (K_ * 8));   \
            p0 = src[l2];                                                     \
            if (l2 < 8) p1 = src[32 + l2];                                    \
        } else {                                                              \
            const float* g = glf + (((size_t)b * 32 + l) * N_ + (NN)) * K_;   \
            p0 = *(const float4*)(g);                                         \
            p1 = *(const float4*)(g + 4);                                     \
            p2 = *(const float4*)(g + 8);                                     \
            p3 = *(const float4*)(g + 12);                                    \
            p4 = *(const float4*)(g + 16);                                    \
        }                                                                     \
    } while (0)

    // issue n0 loads before weight staging so they fly under the barrier
    ISSUE(nw0);

    // ---- one-time weight staging (coalesced global float4 reads) ----
    for (int i = t; i < 64 * 32; i += 512) {          // edge_W: 64x128
        int o = i >> 5, c4 = i & 31;
        float4 v = ((const float4*)edge_W)[i];
        wEdT[(4 * c4 + 0) * 64 + o] = v.x;
        wEdT[(4 * c4 + 1) * 64 + o] = v.y;
        wEdT[(4 * c4 + 2) * 64 + o] = v.z;
        wEdT[(4 * c4 + 3) * 64 + o] = v.w;
    }
    for (int i = t; i < 32 * 16; i += 512) {          // ff_W1: 32x64
        int o = i >> 4, c4 = i & 15;
        float4 v = ((const float4*)ff_W1)[i];
        wF1T[(4 * c4 + 0) * 32 + o] = v.x;
        wF1T[(4 * c4 + 1) * 32 + o] = v.y;
        wF1T[(4 * c4 + 2) * 32 + o] = v.z;
        wF1T[(4 * c4 + 3) * 32 + o] = v.w;
    }
    for (int i = t; i < 64 * 8; i += 512) {           // ff_W2: 64x32
        int o = i >> 3, c4 = i & 7;
        float4 v = ((const float4*)ff_W2)[i];
        wF2T[(4 * c4 + 0) * 64 + o] = v.x;
        wF2T[(4 * c4 + 1) * 64 + o] = v.y;
        wF2T[(4 * c4 + 2) * 64 + o] = v.z;
        wF2T[(4 * c4 + 3) * 64 + o] = v.w;
    }
    __syncthreads();

    // ---- hoisted per-lane constants (n-invariant) ----
    const int o16 = l >> 2, o32 = l >> 1;
    const int kq5 = (l & 3) * 5, kh10 = (l & 1) * 10;
    const float bdk1h = dk_b1[o16], gdk1h = dk_g1[o16], bedk1h = dk_be1[o16];
    const float bdk2h = dk_b2[o32];
    const float gff1h = ff_g1[o32], beff1h = ff_be1[o32];
    const float gacth = act_g[l],  bacth = act_b[l];
    const float gedgh = edge_g[l], beedgh = edge_be[l];
    const float4 wd1a = *(const float4*)(dk_W1 + o16 * 8);
    const float4 wd1b = *(const float4*)(dk_W1 + o16 * 8 + 4);
    const float4 wd20 = *(const float4*)(dk_W2 + o32 * 16);
    const float4 wd21 = *(const float4*)(dk_W2 + o32 * 16 + 4);
    const float4 wd22 = *(const float4*)(dk_W2 + o32 * 16 + 8);
    const float4 wd23 = *(const float4*)(dk_W2 + o32 * 16 + 12);

#pragma unroll 1
    for (int i = 0; i < NPW; ++i) {
        const int n = nw0 + i;

        // ---- commit prefetched per-n data to LDS ----
        const float xc = xcP;
        XCOL[l] = xc;
        if (l < K_) IDX[l] = idxP;
        if (l >= 32) {                 // appf: 160 contiguous floats
            *(float4*)(SCR + 4 * l2) = p0;
            if (l2 < 8) *(float4*)(SCR + 128 + 4 * l2) = p1;
        } else {                       // glf row c2=l -> RIF[k][32+l]
            RIF[ 0 * 64 + 32 + l] = p0.x;
            RIF[ 1 * 64 + 32 + l] = p0.y;
            RIF[ 2 * 64 + 32 + l] = p0.z;
            RIF[ 3 * 64 + 32 + l] = p0.w;
            RIF[ 4 * 64 + 32 + l] = p1.x;
            RIF[ 5 * 64 + 32 + l] = p1.y;
            RIF[ 6 * 64 + 32 + l] = p1.z;
            RIF[ 7 * 64 + 32 + l] = p1.w;
            RIF[ 8 * 64 + 32 + l] = p2.x;
            RIF[ 9 * 64 + 32 + l] = p2.y;
            RIF[10 * 64 + 32 + l] = p2.z;
            RIF[11 * 64 + 32 + l] = p2.w;
            RIF[12 * 64 + 32 + l] = p3.x;
            RIF[13 * 64 + 32 + l] = p3.y;
            RIF[14 * 64 + 32 + l] = p3.z;
            RIF[15 * 64 + 32 + l] = p3.w;
            RIF[16 * 64 + 32 + l] = p4.x;
            RIF[17 * 64 + 32 + l] = p4.y;
            RIF[18 * 64 + 32 + l] = p4.z;
            RIF[19 * 64 + 32 + l] = p4.w;
        }

        // ---- issue next-n global loads (latency hides under this n's FMAs) ----
        if (i + 1 < NPW) ISSUE(n + 1);

        // ---- base_l = edge_W[l, 64:128] . x  (weights from LDS) ----
        float base = 0.f;
#pragma unroll
        for (int c = 0; c < 16; ++c) {
            const float w0 = wEdT[(64 + 4 * c + 0) * 64 + l];
            const float w1 = wEdT[(64 + 4 * c + 1) * 64 + l];
            const float w2 = wEdT[(64 + 4 * c + 2) * 64 + l];
            const float w3 = wEdT[(64 + 4 * c + 3) * 64 + l];
            float4 x4 = *(const float4*)(XCOL + 4 * c);
            base = fmaf(w0, x4.x, base); base = fmaf(w1, x4.y, base);
            base = fmaf(w2, x4.z, base); base = fmaf(w3, x4.w, base);
        }

        // ---- h = relu(bn(dk_W1 @ appf + b1)) : lane -> o=l>>2, k=kq5+q ----
#pragma unroll
        for (int q = 0; q < 5; ++q) {
            const int k = kq5 + q;
            float4 a0 = *(const float4*)(SCR + k * 8);
            float4 a1 = *(const float4*)(SCR + k * 8 + 4);
            float acc = bdk1h;
            acc = fmaf(wd1a.x, a0.x, acc); acc = fmaf(wd1a.y, a0.y, acc);
            acc = fmaf(wd1a.z, a0.z, acc); acc = fmaf(wd1a.w, a0.w, acc);
            acc = fmaf(wd1b.x, a1.x, acc); acc = fmaf(wd1b.y, a1.y, acc);
            acc = fmaf(wd1b.z, a1.z, acc); acc = fmaf(wd1b.w, a1.w, acc);
            float v = acc * gdk1h + bedk1h;
            SCR[160 + k * 16 + o16] = fmaxf(v, 0.f);
        }

        // ---- rif[0:32] = dk_W2 @ h + b2 : lane -> o=l>>1, k=kh10+q ----
#pragma unroll
        for (int q = 0; q < 10; ++q) {
            const int k = kh10 + q;
            const float* hr = SCR + 160 + k * 16;
            float4 h0 = *(const float4*)(hr);
            float4 h1 = *(const float4*)(hr + 4);
            float4 h2 = *(const float4*)(hr + 8);
            float4 h3 = *(const float4*)(hr + 12);
            float acc = bdk2h;
            acc = fmaf(wd20.x, h0.x, acc); acc = fmaf(wd20.y, h0.y, acc);
            acc = fmaf(wd20.z, h0.z, acc); acc = fmaf(wd20.w, h0.w, acc);
            acc = fmaf(wd21.x, h1.x, acc); acc = fmaf(wd21.y, h1.y, acc);
            acc = fmaf(wd21.z, h1.z, acc); acc = fmaf(wd21.w, h1.w, acc);
            acc = fmaf(wd22.x, h2.x, acc); acc = fmaf(wd22.y, h2.y, acc);
            acc = fmaf(wd22.z, h2.z, acc); acc = fmaf(wd22.w, h2.w, acc);
            acc = fmaf(wd23.x, h3.x, acc); acc = fmaf(wd23.y, h3.y, acc);
            acc = fmaf(wd23.z, h3.z, acc); acc = fmaf(wd23.w, h3.w, acc);
            RIF[k * 64 + o32] = acc;
        }

        // ---- t = leaky(bn(ff_W1 @ rif)) : lane -> o=l>>1, k=kh10+q ----
        {
            float acc[10];
#pragma unroll
            for (int q = 0; q < 10; ++q) acc[q] = 0.f;
#pragma unroll
            for (int c = 0; c < 16; ++c) {
                const float w0 = wF1T[(4 * c + 0) * 32 + o32];
                const float w1 = wF1T[(4 * c + 1) * 32 + o32];
                const float w2 = wF1T[(4 * c + 2) * 32 + o32];
                const float w3 = wF1T[(4 * c + 3) * 32 + o32];
#pragma unroll
                for (int q = 0; q < 10; ++q) {
                    float4 r4 = *(const float4*)(RIF + (kh10 + q) * 64 + 4 * c);
                    acc[q] = fmaf(w0, r4.x, acc[q]);
                    acc[q] = fmaf(w1, r4.y, acc[q]);
                    acc[q] = fmaf(w2, r4.z, acc[q]);
                    acc[q] = fmaf(w3, r4.w, acc[q]);
                }
            }
#pragma unroll
            for (int q = 0; q < 10; ++q) {
                float v = acc[q] * gff1h + beff1h;
                v = (v >= 0.f) ? v : NEG_SLOPE * v;
                SCR[(kh10 + q) * 32 + o32] = v;   // t overwrites appf/h (dead)
            }
        }

        // ---- att = sigmoid(ff_W2 @ t); feat = relu(bn(rif*att*gather)) - x ----
        float acc2[20];
#pragma unroll
        for (int k = 0; k < 20; ++k) acc2[k] = 0.f;
#pragma unroll
        for (int c = 0; c < 8; ++c) {
            const float w0 = wF2T[(4 * c + 0) * 64 + l];
            const float w1 = wF2T[(4 * c + 1) * 64 + l];
            const float w2 = wF2T[(4 * c + 2) * 64 + l];
            const float w3 = wF2T[(4 * c + 3) * 64 + l];
#pragma unroll
            for (int k = 0; k < 20; ++k) {
                float4 t4 = *(const float4*)(SCR + k * 32 + 4 * c);
                acc2[k] = fmaf(w0, t4.x, acc2[k]);
                acc2[k] = fmaf(w1, t4.y, acc2[k]);
                acc2[k] = fmaf(w2, t4.z, acc2[k]);
                acc2[k] = fmaf(w3, t4.w, acc2[k]);
            }
        }
#pragma unroll
        for (int k = 0; k < 20; ++k) {
            float a = 1.f / (1.f + expf(-acc2[k]));
            int kidx = IDX[k];
            float gth = bxb[(size_t)kidx * 64 + l];   // coalesced 256 B row
            float v = RIF[k * 64 + l] * a * gth;
            v = v * gacth + bacth;
            v = fmaxf(v, 0.f) - xc;
            RIF[k * 64 + l] = v;
        }

        // ---- edge conv + bn + leaky + max over k (weights from LDS) ----
#pragma unroll
        for (int k = 0; k < 20; ++k) acc2[k] = base;
#pragma unroll
        for (int c = 0; c < 16; ++c) {
            const float w0 = wEdT[(4 * c + 0) * 64 + l];
            const float w1 = wEdT[(4 * c + 1) * 64 + l];
            const float w2 = wEdT[(4 * c + 2) * 64 + l];
            const float w3 = wEdT[(4 * c + 3) * 64 + l];
#pragma unroll
            for (int k = 0; k < 20; ++k) {
                float4 r4 = *(const float4*)(RIF + k * 64 + 4 * c);
                acc2[k] = fmaf(w0, r4.x, acc2[k]);
                acc2[k] = fmaf(w1, r4.y, acc2[k]);
                acc2[k] = fmaf(w2, r4.z, acc2[k]);
                acc2[k] = fmaf(w3, r4.w, acc2[k]);
            }
        }
        float mx = -INFINITY;
#pragma unroll
        for (int k = 0; k < 20; ++k) {
            float v = acc2[k] * gedgh + beedgh;
            v = (v >= 0.f) ? v : NEG_SLOPE * v;
            mx = fmaxf(mx, v);
        }
        out[((size_t)b * OUT_ + l) * N_ + n] = mx;
    }
#undef ISSUE
}

// ---------------------------------------------------------------------------
extern "C" void kernel_launch(void* const* d_in, const int* in_sizes, int n_in,
                              void* d_out, int out_size, void* d_ws, size_t ws_size,
                              hipStream_t stream) {
    (void)in_sizes; (void)n_in; (void)out_size; (void)ws_size;
    const float* pos     = (const float*)d_in[0];
    const float* x       = (const float*)d_in[1];
    const float* glf     = (const float*)d_in[2];
    const float* appf    = (const float*)d_in[3];
    const float* basis_W = (const float*)d_in[4];
    const float* dk_W1   = (const float*)d_in[5];
    const float* dk_b1   = (const float*)d_in[6];
    const float* dk_g1   = (const float*)d_in[7];
    const float* dk_be1  = (const float*)d_in[8];
    const float* dk_W2   = (const float*)d_in[9];
    const float* dk_b2   = (const float*)d_in[10];
    const float* act_g   = (const float*)d_in[11];
    const float* act_b   = (const float*)d_in[12];
    const float* ff_W1   = (const float*)d_in[13];
    const float* ff_g1   = (const float*)d_in[14];
    const float* ff_be1  = (const float*)d_in[15];
    const float* ff_W2   = (const float*)d_in[16];
    const float* edge_W  = (const float*)d_in[17];
    const float* edge_g  = (const float*)d_in[18];
    const float* edge_be = (const float*)d_in[19];
    float* out = (float*)d_out;

    int*   idx_ws = (int*)d_ws;
    float* bxT    = (float*)((char*)d_ws + (size_t)B_ * N_ * K_ * sizeof(int));

    hipLaunchKernelGGL(knn_kernel, dim3(B_ * N_ / 4), dim3(256), 0, stream,
                       pos, idx_ws);
    hipLaunchKernelGGL(bx_kernel_t, dim3(N_ / 32, B_), dim3(256), 0, stream,
                       x, basis_W, bxT);
    hipLaunchKernelGGL(fused_kernel, dim3(B_ * (N_ / NBLK)), dim3(512), 0, stream,
                       x, glf, appf, dk_W1, dk_b1, dk_g1, dk_be1, dk_W2, dk_b2,
                       act_g, act_b, ff_W1, ff_g1, ff_be1, ff_W2,
                       edge_W, edge_g, edge_be, bxT, idx_ws, out);
}

// Round 8
// 995.726 us; speedup vs baseline: 1.3917x; 1.1320x over previous
//
#include <hip/hip_runtime.h>
#include <math.h>

#define B_   16
#define N_   2048
#define K_   20
#define C_   64
#define OUT_ 64
#define NEG_SLOPE 0.2f

#define IDX_BYTES   ((size_t)B_ * N_ * K_ * sizeof(int))     // 2.62 MB
#define BXT_BYTES   ((size_t)B_ * N_ * 64 * sizeof(float))   // 8.39 MB
#define BASET_BYTES ((size_t)B_ * N_ * 64 * sizeof(float))   // 8.39 MB
#define FEAT_CHUNK_BYTES(CB) ((size_t)(CB) * N_ * 20 * 64 * sizeof(float))

// ---------------------------------------------------------------------------
// Kernel 1: KNN — one wave per point (bit-identical math, unchanged).
// ---------------------------------------------------------------------------
__global__ __launch_bounds__(256, 2)
void knn_kernel(const float* __restrict__ pos, int* __restrict__ idx_out) {
    const int t = threadIdx.x;
    const int wv = t >> 6, l = t & 63;
    const int gid = blockIdx.x * 4 + wv;
    const int b = gid / N_, n = gid % N_;
    const float* pb = pos + (size_t)b * 3 * N_;

    const double qx = (double)pb[n];
    const double qy = (double)pb[N_ + n];
    const double qz = (double)pb[2 * N_ + n];
    const double xxn = qx * qx + qy * qy + qz * qz;

    double d[32];
    const int m0 = l * 32;
#pragma unroll
    for (int j4 = 0; j4 < 8; ++j4) {
        float4 px = *(const float4*)(pb + m0 + 4 * j4);
        float4 py = *(const float4*)(pb + N_ + m0 + 4 * j4);
        float4 pz = *(const float4*)(pb + 2 * N_ + m0 + 4 * j4);
#define DCOMP(JJ, PX, PY, PZ)                                            \
        {   double ddx = (double)(PX), ddy = (double)(PY), ddz = (double)(PZ); \
            double inner = qx * ddx + qy * ddy + qz * ddz;               \
            double xxm   = ddx * ddx + ddy * ddy + ddz * ddz;            \
            d[4 * j4 + JJ] = 2.0 * inner - xxn - xxm; }
        DCOMP(0, px.x, py.x, pz.x)
        DCOMP(1, px.y, py.y, pz.y)
        DCOMP(2, px.z, py.z, pz.z)
        DCOMP(3, px.w, py.w, pz.w)
#undef DCOMP
    }

    unsigned sel = 0u;
    for (int r = 0; r < K_ + 1; ++r) {
        double bk = -INFINITY;
        int bi = 0x7FFFFFFF;
#pragma unroll
        for (int j = 0; j < 32; ++j) {
            bool live = ((sel >> j) & 1u) == 0u;
            if (live && d[j] > bk) { bk = d[j]; bi = m0 + j; }
        }
#pragma unroll
        for (int off = 1; off < 64; off <<= 1) {
            double ok = __shfl_xor(bk, off, 64);
            int    oi = __shfl_xor(bi, off, 64);
            if (ok > bk || (ok == bk && oi < bi)) { bk = ok; bi = oi; }
        }
        if ((bi >> 5) == l) sel |= 1u << (bi & 31);
        if (l == 0 && r > 0) idx_out[(size_t)gid * K_ + (r - 1)] = bi;
    }
}

// ---------------------------------------------------------------------------
// Kernel 2: bxT[b][n][o] = basis_W @ x  AND  baseT[b][n][o] = edge_W[:,64:128] @ x
// (x staged once; base moved here from the fused kernel — R13 split.)
// ---------------------------------------------------------------------------
__global__ __launch_bounds__(256)
void bx_base_kernel(const float* __restrict__ x, const float* __restrict__ W,
                    const float* __restrict__ edgeW,
                    float* __restrict__ bxT, float* __restrict__ baseT) {
    __shared__ float wS[64 * 65];
    __shared__ float wE[64 * 65];
    __shared__ float xS[64 * 33];
    const int t = threadIdx.x;
    const int b = blockIdx.y;
    const int n0 = blockIdx.x * 32;

    for (int i = t; i < 64 * 64; i += 256) {
        int r = i >> 6, c = i & 63;
        wS[r * 65 + c] = W[i];
        wE[r * 65 + c] = edgeW[r * 128 + 64 + c];
    }
    for (int i = t; i < 64 * 32; i += 256) {
        int c = i >> 5, j = i & 31;
        xS[c * 33 + j] = x[((size_t)b * C_ + c) * N_ + n0 + j];
    }
    __syncthreads();

    const int o = t & 63, j0 = t >> 6;
#pragma unroll 1
    for (int j = j0; j < 32; j += 4) {
        float acc = 0.f, acb = 0.f;
#pragma unroll
        for (int c = 0; c < 64; ++c) {
            float xv = xS[c * 33 + j];
            acc = fmaf(wS[o * 65 + c], xv, acc);
            acb = fmaf(wE[o * 65 + c], xv, acb);
        }
        bxT  [((size_t)b * N_ + n0 + j) * 64 + o] = acc;
        baseT[((size_t)b * N_ + n0 + j) * 64 + o] = acb;
    }
}

// ---------------------------------------------------------------------------
// Kernel 3a (R13): feat pipeline — load -> dk1 -> dk2 -> ff1 -> ff2+gather,
// writes feat (= relu(bn(rif*att*gather)) - x) to workspace.
// Register demand ~95 (one acc2[20] phase, no edge_W/edge phase, no base)
// -> fits the 128 cap WITHOUT spilling. LDS 48 KB -> 3 blocks/CU.
// ---------------------------------------------------------------------------
#define SLICE 2048         // floats per wave slice (8 KB)

__global__ __launch_bounds__(256, 2)
void feat_kernel(const float* __restrict__ x, const float* __restrict__ glf,
                 const float* __restrict__ appf,
                 const float* __restrict__ dk_W1, const float* __restrict__ dk_b1,
                 const float* __restrict__ dk_g1, const float* __restrict__ dk_be1,
                 const float* __restrict__ dk_W2, const float* __restrict__ dk_b2,
                 const float* __restrict__ act_g, const float* __restrict__ act_b,
                 const float* __restrict__ ff_W1, const float* __restrict__ ff_g1,
                 const float* __restrict__ ff_be1, const float* __restrict__ ff_W2,
                 const float* __restrict__ bxT, const int* __restrict__ idx_ws,
                 float* __restrict__ featW, int b0) {
    __shared__ float wF1T[64 * 32];    // wF1T[c][o] = ff_W1[o][c]    (8 KB)
    __shared__ float wF2T[32 * 64];    // wF2T[c][o] = ff_W2[o][c]    (8 KB)
    __shared__ float lds[4 * SLICE];   // per-wave slices             (32 KB)

    const int t = threadIdx.x, wv = t >> 6, l = t & 63;
    float* Wb   = lds + wv * SLICE;
    float* RIF  = Wb;                  // [20][64]
    float* SCR  = Wb + 1280;           // appf [20][8] ; h [20][16]@160 ; t [20][32]@0
    int*   IDX  = (int*)(Wb + 1920);   // 20

    for (int i = t; i < 32 * 16; i += 256) {          // ff_W1: 32x64
        int o = i >> 4, c4 = i & 15;
        float4 v = ((const float4*)ff_W1)[i];
        wF1T[(4 * c4 + 0) * 32 + o] = v.x;
        wF1T[(4 * c4 + 1) * 32 + o] = v.y;
        wF1T[(4 * c4 + 2) * 32 + o] = v.z;
        wF1T[(4 * c4 + 3) * 32 + o] = v.w;
    }
    for (int i = t; i < 64 * 8; i += 256) {           // ff_W2: 64x32
        int o = i >> 3, c4 = i & 7;
        float4 v = ((const float4*)ff_W2)[i];
        wF2T[(4 * c4 + 0) * 64 + o] = v.x;
        wF2T[(4 * c4 + 1) * 64 + o] = v.y;
        wF2T[(4 * c4 + 2) * 64 + o] = v.z;
        wF2T[(4 * c4 + 3) * 64 + o] = v.w;
    }
    __syncthreads();

    // Swizzle: grid = CB*128 blocks; per b: 128 blocks = 8 xcd x 16 slots.
    const int raw  = blockIdx.x;
    const int xcd  = raw & 7;
    const int slot = raw >> 3;
    const int b    = b0 + (slot >> 4);
    const int nslot= xcd * 16 + (slot & 15);          // 0..127
    const int nw0  = nslot * 16 + wv * 4;

    const int o16 = l >> 2, o32 = l >> 1;
    const int kq5 = (l & 3) * 5, kh10 = (l & 1) * 10;
    const int l2 = l & 31;
    const float bdk1h = dk_b1[o16], gdk1h = dk_g1[o16], bedk1h = dk_be1[o16];
    const float bdk2h = dk_b2[o32];
    const float gff1h = ff_g1[o32], beff1h = ff_be1[o32];
    const float gacth = act_g[l],  bacth = act_b[l];
    const float4 wd1a = *(const float4*)(dk_W1 + o16 * 8);
    const float4 wd1b = *(const float4*)(dk_W1 + o16 * 8 + 4);
    const float4 wd20 = *(const float4*)(dk_W2 + o32 * 16);
    const float4 wd21 = *(const float4*)(dk_W2 + o32 * 16 + 4);
    const float4 wd22 = *(const float4*)(dk_W2 + o32 * 16 + 8);
    const float4 wd23 = *(const float4*)(dk_W2 + o32 * 16 + 12);
    const float* xrow = x + ((size_t)b * C_ + l) * N_;
    const float* bxb  = bxT + (size_t)b * N_ * 64;

#pragma unroll 1
    for (int i = 0; i < 4; ++i) {
        const int n = nw0 + i;
        const size_t bnloc = (size_t)(b - b0) * N_ + n;

        // ---- per-n loads ----
        const float xc = xrow[n];
        if (l < K_) IDX[l] = idx_ws[((size_t)b * N_ + n) * K_ + l];
        if (l >= 32) {                 // appf: 160 contiguous floats
            const float4* src = (const float4*)(appf + ((size_t)b * N_ + n) * (K_ * 8));
            *(float4*)(SCR + 4 * l2) = src[l2];
            if (l2 < 8) *(float4*)(SCR + 128 + 4 * l2) = src[32 + l2];
        } else {                       // glf row c2=l -> RIF[k][32+l]
            const float* g = glf + (((size_t)b * 32 + l) * N_ + n) * K_;
#pragma unroll
            for (int kc = 0; kc < 5; ++kc) {
                float4 v = *(const float4*)(g + 4 * kc);
                RIF[(4 * kc + 0) * 64 + 32 + l] = v.x;
                RIF[(4 * kc + 1) * 64 + 32 + l] = v.y;
                RIF[(4 * kc + 2) * 64 + 32 + l] = v.z;
                RIF[(4 * kc + 3) * 64 + 32 + l] = v.w;
            }
        }

        // ---- h = relu(bn(dk_W1 @ appf + b1)) : lane -> o=l>>2, k=kq5+q ----
#pragma unroll
        for (int q = 0; q < 5; ++q) {
            const int k = kq5 + q;
            float4 a0 = *(const float4*)(SCR + k * 8);
            float4 a1 = *(const float4*)(SCR + k * 8 + 4);
            float acc = bdk1h;
            acc = fmaf(wd1a.x, a0.x, acc); acc = fmaf(wd1a.y, a0.y, acc);
            acc = fmaf(wd1a.z, a0.z, acc); acc = fmaf(wd1a.w, a0.w, acc);
            acc = fmaf(wd1b.x, a1.x, acc); acc = fmaf(wd1b.y, a1.y, acc);
            acc = fmaf(wd1b.z, a1.z, acc); acc = fmaf(wd1b.w, a1.w, acc);
            float v = acc * gdk1h + bedk1h;
            SCR[160 + k * 16 + o16] = fmaxf(v, 0.f);
        }

        // ---- rif[0:32] = dk_W2 @ h + b2 : lane -> o=l>>1, k=kh10+q ----
#pragma unroll
        for (int q = 0; q < 10; ++q) {
            const int k = kh10 + q;
            const float* hr = SCR + 160 + k * 16;
            float4 h0 = *(const float4*)(hr);
            float4 h1 = *(const float4*)(hr + 4);
            float4 h2 = *(const float4*)(hr + 8);
            float4 h3 = *(const float4*)(hr + 12);
            float acc = bdk2h;
            acc = fmaf(wd20.x, h0.x, acc); acc = fmaf(wd20.y, h0.y, acc);
            acc = fmaf(wd20.z, h0.z, acc); acc = fmaf(wd20.w, h0.w, acc);
            acc = fmaf(wd21.x, h1.x, acc); acc = fmaf(wd21.y, h1.y, acc);
            acc = fmaf(wd21.z, h1.z, acc); acc = fmaf(wd21.w, h1.w, acc);
            acc = fmaf(wd22.x, h2.x, acc); acc = fmaf(wd22.y, h2.y, acc);
            acc = fmaf(wd22.z, h2.z, acc); acc = fmaf(wd22.w, h2.w, acc);
            acc = fmaf(wd23.x, h3.x, acc); acc = fmaf(wd23.y, h3.y, acc);
            acc = fmaf(wd23.z, h3.z, acc); acc = fmaf(wd23.w, h3.w, acc);
            RIF[k * 64 + o32] = acc;
        }

        // ---- t = leaky(bn(ff_W1 @ rif)) : lane -> o=l>>1, k=kh10+q ----
        {
            float acc[10];
#pragma unroll
            for (int q = 0; q < 10; ++q) acc[q] = 0.f;
#pragma unroll
            for (int c = 0; c < 16; ++c) {
                const float w0 = wF1T[(4 * c + 0) * 32 + o32];
                const float w1 = wF1T[(4 * c + 1) * 32 + o32];
                const float w2 = wF1T[(4 * c + 2) * 32 + o32];
                const float w3 = wF1T[(4 * c + 3) * 32 + o32];
#pragma unroll
                for (int q = 0; q < 10; ++q) {
                    float4 r4 = *(const float4*)(RIF + (kh10 + q) * 64 + 4 * c);
                    acc[q] = fmaf(w0, r4.x, acc[q]);
                    acc[q] = fmaf(w1, r4.y, acc[q]);
                    acc[q] = fmaf(w2, r4.z, acc[q]);
                    acc[q] = fmaf(w3, r4.w, acc[q]);
                }
            }
#pragma unroll
            for (int q = 0; q < 10; ++q) {
                float v = acc[q] * gff1h + beff1h;
                v = (v >= 0.f) ? v : NEG_SLOPE * v;
                SCR[(kh10 + q) * 32 + o32] = v;   // t overwrites appf/h (dead)
            }
        }

        // ---- att = sigmoid(ff_W2 @ t); feat = relu(bn(rif*att*gather)) - x ----
        float acc2[20];
#pragma unroll
        for (int k = 0; k < 20; ++k) acc2[k] = 0.f;
#pragma unroll
        for (int c = 0; c < 8; ++c) {
            const float w0 = wF2T[(4 * c + 0) * 64 + l];
            const float w1 = wF2T[(4 * c + 1) * 64 + l];
            const float w2 = wF2T[(4 * c + 2) * 64 + l];
            const float w3 = wF2T[(4 * c + 3) * 64 + l];
#pragma unroll
            for (int k = 0; k < 20; ++k) {
                float4 t4 = *(const float4*)(SCR + k * 32 + 4 * c);
                acc2[k] = fmaf(w0, t4.x, acc2[k]);
                acc2[k] = fmaf(w1, t4.y, acc2[k]);
                acc2[k] = fmaf(w2, t4.z, acc2[k]);
                acc2[k] = fmaf(w3, t4.w, acc2[k]);
            }
        }
        float* fdst = featW + bnloc * (20 * 64);
#pragma unroll
        for (int k = 0; k < 20; ++k) {
            float a = 1.f / (1.f + expf(-acc2[k]));
            int kidx = IDX[k];
            float gth = bxb[(size_t)kidx * 64 + l];   // coalesced 256 B row
            float v = RIF[k * 64 + l] * a * gth;
            v = v * gacth + bacth;
            v = fmaxf(v, 0.f) - xc;
            fdst[k * 64 + l] = v;                     // coalesced 256 B store
        }
    }
}

// ---------------------------------------------------------------------------
// Kernel 3b (R13): edge conv + bn + leaky + max over k.
// Reads feat from workspace + baseT. ~60 regs, 36 KB LDS -> 4 blocks/CU.
// FMA order identical to the old edge phase -> bit-identical output.
// ---------------------------------------------------------------------------
__global__ __launch_bounds__(256, 2)
void edge_kernel(const float* __restrict__ edge_W, const float* __restrict__ edge_g,
                 const float* __restrict__ edge_be,
                 const float* __restrict__ featW, const float* __restrict__ baseT,
                 float* __restrict__ out, int b0) {
    __shared__ float wEdT[64 * 64];    // wEdT[c][o] = edge_W[o][c], c<64 (16 KB)
    __shared__ float FSs[4 * 1280];    // per-wave feat slice [20][64]   (20 KB)

    const int t = threadIdx.x, wv = t >> 6, l = t & 63;
    float* FS = FSs + wv * 1280;

    for (int i = t; i < 64 * 16; i += 256) {          // edge_W cols 0..63
        int o = i >> 4, c4 = i & 15;
        float4 v = ((const float4*)edge_W)[o * 32 + c4];
        wEdT[(4 * c4 + 0) * 64 + o] = v.x;
        wEdT[(4 * c4 + 1) * 64 + o] = v.y;
        wEdT[(4 * c4 + 2) * 64 + o] = v.z;
        wEdT[(4 * c4 + 3) * 64 + o] = v.w;
    }
    __syncthreads();

    const int raw  = blockIdx.x;
    const int xcd  = raw & 7;
    const int slot = raw >> 3;
    const int b    = b0 + (slot >> 4);
    const int nslot= xcd * 16 + (slot & 15);
    const int nw0  = nslot * 16 + wv * 4;

    const float gedgh = edge_g[l], beedgh = edge_be[l];

#pragma unroll 1
    for (int i = 0; i < 4; ++i) {
        const int n = nw0 + i;
        const size_t bnloc = (size_t)(b - b0) * N_ + n;

        // stage feat row (1280 contiguous floats) into LDS (wave-local)
        const float4* fsrc = (const float4*)(featW + bnloc * 1280);
#pragma unroll
        for (int j = 0; j < 5; ++j)
            *(float4*)(FS + (j * 64 + l) * 4) = fsrc[j * 64 + l];

        const float base = baseT[((size_t)b * N_ + n) * 64 + l];

        float acc2[20];
#pragma unroll
        for (int k = 0; k < 20; ++k) acc2[k] = base;
#pragma unroll
        for (int c = 0; c < 16; ++c) {
            const float w0 = wEdT[(4 * c + 0) * 64 + l];
            const float w1 = wEdT[(4 * c + 1) * 64 + l];
            const float w2 = wEdT[(4 * c + 2) * 64 + l];
            const float w3 = wEdT[(4 * c + 3) * 64 + l];
#pragma unroll
            for (int k = 0; k < 20; ++k) {
                float4 r4 = *(const float4*)(FS + k * 64 + 4 * c);
                acc2[k] = fmaf(w0, r4.x, acc2[k]);
                acc2[k] = fmaf(w1, r4.y, acc2[k]);
                acc2[k] = fmaf(w2, r4.z, acc2[k]);
                acc2[k] = fmaf(w3, r4.w, acc2[k]);
            }
        }
        float mx = -INFINITY;
#pragma unroll
        for (int k = 0; k < 20; ++k) {
            float v = acc2[k] * gedgh + beedgh;
            v = (v >= 0.f) ? v : NEG_SLOPE * v;
            mx = fmaxf(mx, v);
        }
        out[((size_t)b * OUT_ + l) * N_ + n] = mx;
    }
}

// ---------------------------------------------------------------------------
extern "C" void kernel_launch(void* const* d_in, const int* in_sizes, int n_in,
                              void* d_out, int out_size, void* d_ws, size_t ws_size,
                              hipStream_t stream) {
    (void)in_sizes; (void)n_in; (void)out_size;
    const float* pos     = (const float*)d_in[0];
    const float* x       = (const float*)d_in[1];
    const float* glf     = (const float*)d_in[2];
    const float* appf    = (const float*)d_in[3];
    const float* basis_W = (const float*)d_in[4];
    const float* dk_W1   = (const float*)d_in[5];
    const float* dk_b1   = (const float*)d_in[6];
    const float* dk_g1   = (const float*)d_in[7];
    const float* dk_be1  = (const float*)d_in[8];
    const float* dk_W2   = (const float*)d_in[9];
    const float* dk_b2   = (const float*)d_in[10];
    const float* act_g   = (const float*)d_in[11];
    const float* act_b   = (const float*)d_in[12];
    const float* ff_W1   = (const float*)d_in[13];
    const float* ff_g1   = (const float*)d_in[14];
    const float* ff_be1  = (const float*)d_in[15];
    const float* ff_W2   = (const float*)d_in[16];
    const float* edge_W  = (const float*)d_in[17];
    const float* edge_g  = (const float*)d_in[18];
    const float* edge_be = (const float*)d_in[19];
    float* out = (float*)d_out;

    int*   idx_ws = (int*)d_ws;
    float* bxT    = (float*)((char*)d_ws + IDX_BYTES);
    float* baseT  = (float*)((char*)d_ws + IDX_BYTES + BXT_BYTES);
    float* featW  = (float*)((char*)d_ws + IDX_BYTES + BXT_BYTES + BASET_BYTES);

    const size_t fixed = IDX_BYTES + BXT_BYTES + BASET_BYTES;
    const int CB = (ws_size >= fixed + FEAT_CHUNK_BYTES(4)) ? 4 : 1;

    hipLaunchKernelGGL(knn_kernel, dim3(B_ * N_ / 4), dim3(256), 0, stream,
                       pos, idx_ws);
    hipLaunchKernelGGL(bx_base_kernel, dim3(N_ / 32, B_), dim3(256), 0, stream,
                       x, basis_W, edge_W, bxT, baseT);
    for (int b0 = 0; b0 < B_; b0 += CB) {
        hipLaunchKernelGGL(feat_kernel, dim3(CB * 128), dim3(256), 0, stream,
                           x, glf, appf, dk_W1, dk_b1, dk_g1, dk_be1,
                           dk_W2, dk_b2, act_g, act_b, ff_W1, ff_g1, ff_be1,
                           ff_W2, bxT, idx_ws, featW, b0);
        hipLaunchKernelGGL(edge_kernel, dim3(CB * 128), dim3(256), 0, stream,
                           edge_W, edge_g, edge_be, featW, baseT, out, b0);
    }
}